// Round 1
// baseline (6041.415 us; speedup 1.0000x reference)
//
#include <hip/hip_runtime.h>
#include <cstdint>
#include <cstddef>

#define B_SZ   4
#define N_PTS  16384
#define M_CENT 2048
#define NSAMP  32
#define C_IN   64
#define H1_DIM 64
#define H2_DIM 128
#define FPS_T  1024
#define PPT    (N_PTS / FPS_T)   // 16 points per thread
#define H0_STR 68                // 67 channels padded to 68 for 16B-aligned float4

// ---------------------------------------------------------------------------
// K1: Farthest-point sampling. One block per batch. Points + running dists in
// registers; block-wide (max val, min idx) reduction carries winner coords.
// Bit-exact vs numpy: contract(off), ((dx*dx+dy*dy)+dz*dz), first-occurrence
// argmax tie-break.
// ---------------------------------------------------------------------------
__global__ __launch_bounds__(FPS_T) void fps_kernel(const float* __restrict__ xyz,
                                                    float* __restrict__ out_xyz) {
#pragma clang fp contract(off)
  const int b    = blockIdx.x;
  const int t    = threadIdx.x;
  const int lane = t & 63;
  const int wave = t >> 6;
  const float* bx = xyz + (size_t)b * N_PTS * 3;

  float px[PPT], py[PPT], pz[PPT], pd[PPT];
#pragma unroll
  for (int j = 0; j < PPT; ++j) {
    const int i = j * FPS_T + t;
    px[j] = bx[i * 3 + 0];
    py[j] = bx[i * 3 + 1];
    pz[j] = bx[i * 3 + 2];
    pd[j] = 1e10f;  // BIG
  }

  __shared__ float s_val[16], s_x[16], s_y[16], s_z[16];
  __shared__ int   s_idx[16];
  __shared__ float s_cur[3];

  // current point = index 0 (reference idx0 = 0)
  float cx = bx[0], cy = bx[1], cz = bx[2];
  float* ox = out_xyz + (size_t)b * M_CENT * 3;

  for (int m = 0; m < M_CENT; ++m) {
    if (t == 0) { ox[m * 3 + 0] = cx; ox[m * 3 + 1] = cy; ox[m * 3 + 2] = cz; }
    if (m == M_CENT - 1) break;

    float bv = -1.0f;           // all dists >= 0, sentinel never wins
    int   bi = 0x7fffffff;
    float bpx = 0.f, bpy = 0.f, bpz = 0.f;
#pragma unroll
    for (int j = 0; j < PPT; ++j) {
      const float dx = px[j] - cx, dy = py[j] - cy, dz = pz[j] - cz;
      const float d  = (dx * dx + dy * dy) + dz * dz;   // numpy op order, no FMA
      const float nd = fminf(pd[j], d);
      pd[j] = nd;
      const bool better = nd > bv;   // strict: keeps smaller j (= smaller index)
      bv  = better ? nd    : bv;
      bi  = better ? (j * FPS_T + t) : bi;
      bpx = better ? px[j] : bpx;
      bpy = better ? py[j] : bpy;
      bpz = better ? pz[j] : bpz;
    }
    // wave (64-lane) reduction: max val, tie -> min idx
#pragma unroll
    for (int off = 32; off >= 1; off >>= 1) {
      const float ov = __shfl_down(bv, off);
      const int   oi = __shfl_down(bi, off);
      const float oxx = __shfl_down(bpx, off);
      const float oyy = __shfl_down(bpy, off);
      const float ozz = __shfl_down(bpz, off);
      const bool take = (ov > bv) || (ov == bv && oi < bi);
      bv  = take ? ov  : bv;
      bi  = take ? oi  : bi;
      bpx = take ? oxx : bpx;
      bpy = take ? oyy : bpy;
      bpz = take ? ozz : bpz;
    }
    if (lane == 0) { s_val[wave] = bv; s_idx[wave] = bi; s_x[wave] = bpx; s_y[wave] = bpy; s_z[wave] = bpz; }
    __syncthreads();
    if (wave == 0) {
      if (lane < 16) { bv = s_val[lane]; bi = s_idx[lane]; bpx = s_x[lane]; bpy = s_y[lane]; bpz = s_z[lane]; }
      else           { bv = -1.0f; bi = 0x7fffffff; bpx = 0.f; bpy = 0.f; bpz = 0.f; }
#pragma unroll
      for (int off = 8; off >= 1; off >>= 1) {
        const float ov = __shfl_down(bv, off);
        const int   oi = __shfl_down(bi, off);
        const float oxx = __shfl_down(bpx, off);
        const float oyy = __shfl_down(bpy, off);
        const float ozz = __shfl_down(bpz, off);
        const bool take = (ov > bv) || (ov == bv && oi < bi);
        bv  = take ? ov  : bv;
        bi  = take ? oi  : bi;
        bpx = take ? oxx : bpx;
        bpy = take ? oyy : bpy;
        bpz = take ? ozz : bpz;
      }
      if (lane == 0) { s_cur[0] = bpx; s_cur[1] = bpy; s_cur[2] = bpz; }
    }
    __syncthreads();
    cx = s_cur[0]; cy = s_cur[1]; cz = s_cur[2];
  }
}

// ---------------------------------------------------------------------------
// K2: Ball query. One wave per centroid: ballot + prefix popcount appends the
// first 32 in-radius indices in index order (== top_k(-order) semantics),
// pads with the first hit. Early exit once 32 found.
// ---------------------------------------------------------------------------
__global__ __launch_bounds__(256) void ballq_kernel(const float* __restrict__ xyz,
                                                    const float* __restrict__ new_xyz,
                                                    int* __restrict__ idx_out) {
#pragma clang fp contract(off)
  const int lane = threadIdx.x & 63;
  const int gid  = blockIdx.x * 4 + (threadIdx.x >> 6);
  if (gid >= B_SZ * M_CENT) return;
  const int b = gid >> 11;  // / M_CENT
  const float* bx = xyz + (size_t)b * N_PTS * 3;
  const float cx = new_xyz[gid * 3 + 0];
  const float cy = new_xyz[gid * 3 + 1];
  const float cz = new_xyz[gid * 3 + 2];
  const float rr = (float)(0.8 * 0.8);  // double 0.64 -> f32 0.63999999 (JAX weak-scalar cast)
  int* out = idx_out + (size_t)gid * NSAMP;

  int count = 0;
  int first = -1;
  for (int base = 0; base < N_PTS; base += 64) {
    const int i = base + lane;
    const float dx = bx[i * 3 + 0] - cx;
    const float dy = bx[i * 3 + 1] - cy;
    const float dz = bx[i * 3 + 2] - cz;
    const float d = (dx * dx + dy * dy) + dz * dz;
    const bool pred = d < rr;
    const unsigned long long mk = __ballot(pred);
    if (pred) {
      const int slot = count + __popcll(mk & ((1ULL << lane) - 1ULL));
      if (slot < NSAMP) out[slot] = i;
    }
    if (first < 0 && mk != 0ULL) first = base + (__ffsll((long long)mk) - 1);
    count += __popcll(mk);
    if (count >= NSAMP) break;
  }
  if (count < NSAMP) {
    for (int k = count + lane; k < NSAMP; k += 64) out[k] = first;  // >=1 hit guaranteed (centroid itself, d=0)
  }
}

// ---------------------------------------------------------------------------
// K3: gather + MLP(67->64 relu, 64->128 relu) + max over 32 samples.
// One 128-thread block per centroid. h0/h1 staged in LDS; reads are
// wave-uniform float4 broadcasts; weights coalesced from L1/L2.
// ---------------------------------------------------------------------------
__global__ __launch_bounds__(128) void mlp_kernel(const float* __restrict__ xyz,
                                                  const float* __restrict__ feats,
                                                  const float* __restrict__ new_xyz,
                                                  const int* __restrict__ idx,
                                                  const float* __restrict__ w1,
                                                  const float* __restrict__ b1,
                                                  const float* __restrict__ w2,
                                                  const float* __restrict__ b2,
                                                  float* __restrict__ out_feats) {
  const int gid = blockIdx.x;
  const int t   = threadIdx.x;
  const int b   = gid >> 11;  // / M_CENT

  __shared__ float h0[NSAMP * H0_STR];
  __shared__ float h1[NSAMP * H1_DIM];
  __shared__ int   sidx[NSAMP];

  if (t < NSAMP) sidx[t] = idx[(size_t)gid * NSAMP + t];
  const float cx = new_xyz[gid * 3 + 0];
  const float cy = new_xyz[gid * 3 + 1];
  const float cz = new_xyz[gid * 3 + 2];
  __syncthreads();

  const float* bxyz = xyz + (size_t)b * N_PTS * 3;
  const float* bft  = feats + (size_t)b * N_PTS * C_IN;
  for (int e = t; e < NSAMP * 67; e += 128) {
    const int s = e / 67;
    const int c = e - s * 67;
    const int p = sidx[s];
    float v;
    if (c < 3) {
      const float pc = bxyz[p * 3 + c];
      v = pc - (c == 0 ? cx : (c == 1 ? cy : cz));
    } else {
      v = bft[(size_t)p * C_IN + (c - 3)];
    }
    h0[s * H0_STR + c] = v;
  }
  __syncthreads();

  // layer 1: col = t&63 over H1_DIM, half = t>>6 picks 16 of 32 samples
  {
    const int col  = t & 63;
    const int half = t >> 6;
    float acc[16];
    const float bb = b1[col];
#pragma unroll
    for (int s = 0; s < 16; ++s) acc[s] = bb;
    const float* h0base = h0 + (half * 16) * H0_STR;
    for (int k = 0; k < 64; k += 4) {
      const float w0v = w1[(k + 0) * H1_DIM + col];
      const float w1v = w1[(k + 1) * H1_DIM + col];
      const float w2v = w1[(k + 2) * H1_DIM + col];
      const float w3v = w1[(k + 3) * H1_DIM + col];
#pragma unroll
      for (int s = 0; s < 16; ++s) {
        const float4 h4 = *reinterpret_cast<const float4*>(h0base + s * H0_STR + k);
        acc[s] += h4.x * w0v + h4.y * w1v + h4.z * w2v + h4.w * w3v;
      }
    }
    for (int k = 64; k < 67; ++k) {
      const float wv = w1[k * H1_DIM + col];
#pragma unroll
      for (int s = 0; s < 16; ++s) acc[s] += h0base[s * H0_STR + k] * wv;
    }
#pragma unroll
    for (int s = 0; s < 16; ++s) h1[(half * 16 + s) * H1_DIM + col] = fmaxf(acc[s], 0.0f);
  }
  __syncthreads();

  // layer 2 + max-pool: col = t over H2_DIM
  {
    float acc[32];
    const float bb = b2[t];
#pragma unroll
    for (int s = 0; s < 32; ++s) acc[s] = bb;
    for (int k = 0; k < 64; k += 4) {
      const float w0v = w2[(k + 0) * H2_DIM + t];
      const float w1v = w2[(k + 1) * H2_DIM + t];
      const float w2v = w2[(k + 2) * H2_DIM + t];
      const float w3v = w2[(k + 3) * H2_DIM + t];
#pragma unroll
      for (int s = 0; s < 32; ++s) {
        const float4 h4 = *reinterpret_cast<const float4*>(&h1[s * H1_DIM + k]);
        acc[s] += h4.x * w0v + h4.y * w1v + h4.z * w2v + h4.w * w3v;
      }
    }
    float mx = 0.0f;  // max(relu(v)) == max(0, max(v))
#pragma unroll
    for (int s = 0; s < 32; ++s) mx = fmaxf(mx, acc[s]);
    out_feats[(size_t)gid * H2_DIM + t] = mx;
  }
}

// ---------------------------------------------------------------------------
extern "C" void kernel_launch(void* const* d_in, const int* in_sizes, int n_in,
                              void* d_out, int out_size, void* d_ws, size_t ws_size,
                              hipStream_t stream) {
  const float* xyz   = (const float*)d_in[0];  // (4,16384,3) f32
  const float* feats = (const float*)d_in[1];  // (4,16384,64) f32
  // d_in[2] = bid (unused; output bid is all zeros)
  const float* w1 = (const float*)d_in[3];     // (67,64)
  const float* b1 = (const float*)d_in[4];     // (64,)
  const float* w2 = (const float*)d_in[5];     // (64,128)
  const float* b2 = (const float*)d_in[6];     // (128,)

  float* out       = (float*)d_out;
  float* out_xyz   = out;                                        // (4,2048,3)
  float* out_feats = out + (size_t)B_SZ * M_CENT * 3;            // (4,2048,128)
  float* out_bid   = out_feats + (size_t)B_SZ * M_CENT * H2_DIM; // (4,2048,1) int32 zeros
  int*   idx_ws    = (int*)d_ws;                                 // (4,2048,32) int32, 1 MiB

  hipLaunchKernelGGL(fps_kernel, dim3(B_SZ), dim3(FPS_T), 0, stream, xyz, out_xyz);
  hipLaunchKernelGGL(ballq_kernel, dim3((B_SZ * M_CENT + 3) / 4), dim3(256), 0, stream,
                     xyz, out_xyz, idx_ws);
  hipLaunchKernelGGL(mlp_kernel, dim3(B_SZ * M_CENT), dim3(128), 0, stream,
                     xyz, feats, out_xyz, idx_ws, w1, b1, w2, b2, out_feats);
  hipMemsetAsync(out_bid, 0, (size_t)B_SZ * M_CENT * sizeof(int), stream);
}

// Round 2
// 4275.519 us; speedup vs baseline: 1.4130x; 1.4130x over previous
//
#include <hip/hip_runtime.h>
#include <cstdint>
#include <cstddef>

#define B_SZ   4
#define N_PTS  16384
#define M_CENT 2048
#define NSAMP  32
#define C_IN   64
#define H1_DIM 64
#define H2_DIM 128
#define FPS_T  1024
#define PPT    (N_PTS / FPS_T)   // 16 points per thread
#define H0_STR 68                // 67 channels padded to 68 for 16B-aligned float4

// ---------------------------------------------------------------------------
// K1: Farthest-point sampling. One block per batch. Points + running dists in
// registers (launch_bounds(1024,4) -> 128 VGPR cap, no spills). Inner loop
// tracks (dist,idx) only; winner coords re-fetched via wave-uniform global
// broadcast load (L1-hot). One barrier/iter, double-buffered LDS keys,
// u64-packed (dist, N-idx) max reduction = exact numpy argmax semantics
// (max dist, first occurrence on ties). contract(off) + ((dx*dx+dy*dy)+dz*dz)
// keeps distances bit-exact vs numpy.
// ---------------------------------------------------------------------------
__global__ __launch_bounds__(FPS_T, 4) void fps_kernel(const float* __restrict__ xyz,
                                                       float* __restrict__ out_xyz) {
#pragma clang fp contract(off)
  const int b    = blockIdx.x;
  const int t    = threadIdx.x;
  const int lane = t & 63;
  const int wave = t >> 6;
  const float* bx = xyz + (size_t)b * N_PTS * 3;
  float* ox = out_xyz + (size_t)b * M_CENT * 3;

  float px[PPT], py[PPT], pz[PPT], pd[PPT];
#pragma unroll
  for (int j = 0; j < PPT; ++j) {
    const int i = j * FPS_T + t;
    px[j] = bx[i * 3 + 0];
    py[j] = bx[i * 3 + 1];
    pz[j] = bx[i * 3 + 2];
    pd[j] = 1e10f;  // BIG
  }

  __shared__ unsigned long long s_key[2][16];

  int cur = 0;  // reference idx0 = 0
  for (int m = 0; m < M_CENT; ++m) {
    // wave-uniform broadcast load of current centroid coords (L1 hit)
    const float cx = bx[cur * 3 + 0];
    const float cy = bx[cur * 3 + 1];
    const float cz = bx[cur * 3 + 2];
    if (t == 0) { ox[m * 3 + 0] = cx; ox[m * 3 + 1] = cy; ox[m * 3 + 2] = cz; }
    if (m == M_CENT - 1) break;

    float bv = -1.0f;  // dists >= 0, so first point always taken
    int   bi = 0;
#pragma unroll
    for (int j = 0; j < PPT; ++j) {
      const float dx = px[j] - cx, dy = py[j] - cy, dz = pz[j] - cz;
      const float d  = (dx * dx + dy * dy) + dz * dz;   // numpy op order, no FMA
      const float nd = fminf(pd[j], d);
      pd[j] = nd;
      const bool better = nd > bv;   // strict: keeps smaller j (= smaller global idx)
      bv = better ? nd : bv;
      bi = better ? (j * FPS_T + t) : bi;
    }
    // pack: high = float bits (>=0, monotone), low = N-idx so ties -> min idx
    unsigned long long key = ((unsigned long long)__float_as_uint(bv) << 32)
                           | (unsigned int)(N_PTS - bi);
    // 64-lane butterfly max
#pragma unroll
    for (int off = 32; off >= 1; off >>= 1) {
      const unsigned long long o = __shfl_xor(key, off);
      key = (key > o) ? key : o;
    }
    const int p = m & 1;
    if (lane == 0) s_key[p][wave] = key;
    __syncthreads();
    // all waves redundantly reduce the 16 per-wave keys (no 2nd barrier)
    key = s_key[p][lane & 15];
#pragma unroll
    for (int off = 8; off >= 1; off >>= 1) {
      const unsigned long long o = __shfl_xor(key, off);
      key = (key > o) ? key : o;
    }
    cur = N_PTS - (int)(key & 0xFFFFFFFFULL);
  }
}

// ---------------------------------------------------------------------------
// K2: Ball query. One wave per centroid: ballot + prefix popcount appends the
// first 32 in-radius indices in index order (== top_k(-order) semantics),
// pads with the first hit. Early exit once 32 found.
// ---------------------------------------------------------------------------
__global__ __launch_bounds__(256) void ballq_kernel(const float* __restrict__ xyz,
                                                    const float* __restrict__ new_xyz,
                                                    int* __restrict__ idx_out) {
#pragma clang fp contract(off)
  const int lane = threadIdx.x & 63;
  const int gid  = blockIdx.x * 4 + (threadIdx.x >> 6);
  if (gid >= B_SZ * M_CENT) return;
  const int b = gid >> 11;  // / M_CENT
  const float* bx = xyz + (size_t)b * N_PTS * 3;
  const float cx = new_xyz[gid * 3 + 0];
  const float cy = new_xyz[gid * 3 + 1];
  const float cz = new_xyz[gid * 3 + 2];
  const float rr = (float)(0.8 * 0.8);  // double 0.64 -> f32 (JAX weak-scalar cast)
  int* out = idx_out + (size_t)gid * NSAMP;

  int count = 0;
  int first = -1;
  for (int base = 0; base < N_PTS; base += 64) {
    const int i = base + lane;
    const float dx = bx[i * 3 + 0] - cx;
    const float dy = bx[i * 3 + 1] - cy;
    const float dz = bx[i * 3 + 2] - cz;
    const float d = (dx * dx + dy * dy) + dz * dz;
    const bool pred = d < rr;
    const unsigned long long mk = __ballot(pred);
    if (pred) {
      const int slot = count + __popcll(mk & ((1ULL << lane) - 1ULL));
      if (slot < NSAMP) out[slot] = i;
    }
    if (first < 0 && mk != 0ULL) first = base + (__ffsll((long long)mk) - 1);
    count += __popcll(mk);
    if (count >= NSAMP) break;
  }
  if (count < NSAMP) {
    for (int k = count + lane; k < NSAMP; k += 64) out[k] = first;  // centroid itself is a hit
  }
}

// ---------------------------------------------------------------------------
// K3: gather + MLP(67->64 relu, 64->128 relu) + max over 32 samples.
// One 128-thread block per centroid. h0/h1 staged in LDS; reads are
// wave-uniform float4 broadcasts; weights coalesced from L1/L2.
// ---------------------------------------------------------------------------
__global__ __launch_bounds__(128) void mlp_kernel(const float* __restrict__ xyz,
                                                  const float* __restrict__ feats,
                                                  const float* __restrict__ new_xyz,
                                                  const int* __restrict__ idx,
                                                  const float* __restrict__ w1,
                                                  const float* __restrict__ b1,
                                                  const float* __restrict__ w2,
                                                  const float* __restrict__ b2,
                                                  float* __restrict__ out_feats) {
  const int gid = blockIdx.x;
  const int t   = threadIdx.x;
  const int b   = gid >> 11;  // / M_CENT

  __shared__ float h0[NSAMP * H0_STR];
  __shared__ float h1[NSAMP * H1_DIM];
  __shared__ int   sidx[NSAMP];

  if (t < NSAMP) sidx[t] = idx[(size_t)gid * NSAMP + t];
  const float cx = new_xyz[gid * 3 + 0];
  const float cy = new_xyz[gid * 3 + 1];
  const float cz = new_xyz[gid * 3 + 2];
  __syncthreads();

  const float* bxyz = xyz + (size_t)b * N_PTS * 3;
  const float* bft  = feats + (size_t)b * N_PTS * C_IN;
  for (int e = t; e < NSAMP * 67; e += 128) {
    const int s = e / 67;
    const int c = e - s * 67;
    const int p = sidx[s];
    float v;
    if (c < 3) {
      const float pc = bxyz[p * 3 + c];
      v = pc - (c == 0 ? cx : (c == 1 ? cy : cz));
    } else {
      v = bft[(size_t)p * C_IN + (c - 3)];
    }
    h0[s * H0_STR + c] = v;
  }
  __syncthreads();

  // layer 1: col = t&63 over H1_DIM, half = t>>6 picks 16 of 32 samples
  {
    const int col  = t & 63;
    const int half = t >> 6;
    float acc[16];
    const float bb = b1[col];
#pragma unroll
    for (int s = 0; s < 16; ++s) acc[s] = bb;
    const float* h0base = h0 + (half * 16) * H0_STR;
    for (int k = 0; k < 64; k += 4) {
      const float w0v = w1[(k + 0) * H1_DIM + col];
      const float w1v = w1[(k + 1) * H1_DIM + col];
      const float w2v = w1[(k + 2) * H1_DIM + col];
      const float w3v = w1[(k + 3) * H1_DIM + col];
#pragma unroll
      for (int s = 0; s < 16; ++s) {
        const float4 h4 = *reinterpret_cast<const float4*>(h0base + s * H0_STR + k);
        acc[s] += h4.x * w0v + h4.y * w1v + h4.z * w2v + h4.w * w3v;
      }
    }
    for (int k = 64; k < 67; ++k) {
      const float wv = w1[k * H1_DIM + col];
#pragma unroll
      for (int s = 0; s < 16; ++s) acc[s] += h0base[s * H0_STR + k] * wv;
    }
#pragma unroll
    for (int s = 0; s < 16; ++s) h1[(half * 16 + s) * H1_DIM + col] = fmaxf(acc[s], 0.0f);
  }
  __syncthreads();

  // layer 2 + max-pool: col = t over H2_DIM
  {
    float acc[32];
    const float bb = b2[t];
#pragma unroll
    for (int s = 0; s < 32; ++s) acc[s] = bb;
    for (int k = 0; k < 64; k += 4) {
      const float w0v = w2[(k + 0) * H2_DIM + t];
      const float w1v = w2[(k + 1) * H2_DIM + t];
      const float w2v = w2[(k + 2) * H2_DIM + t];
      const float w3v = w2[(k + 3) * H2_DIM + t];
#pragma unroll
      for (int s = 0; s < 32; ++s) {
        const float4 h4 = *reinterpret_cast<const float4*>(&h1[s * H1_DIM + k]);
        acc[s] += h4.x * w0v + h4.y * w1v + h4.z * w2v + h4.w * w3v;
      }
    }
    float mx = 0.0f;  // max(relu(v)) == max(0, max(v))
#pragma unroll
    for (int s = 0; s < 32; ++s) mx = fmaxf(mx, acc[s]);
    out_feats[(size_t)gid * H2_DIM + t] = mx;
  }
}

// ---------------------------------------------------------------------------
extern "C" void kernel_launch(void* const* d_in, const int* in_sizes, int n_in,
                              void* d_out, int out_size, void* d_ws, size_t ws_size,
                              hipStream_t stream) {
  const float* xyz   = (const float*)d_in[0];  // (4,16384,3) f32
  const float* feats = (const float*)d_in[1];  // (4,16384,64) f32
  // d_in[2] = bid (unused; output bid is all zeros)
  const float* w1 = (const float*)d_in[3];     // (67,64)
  const float* b1 = (const float*)d_in[4];     // (64,)
  const float* w2 = (const float*)d_in[5];     // (64,128)
  const float* b2 = (const float*)d_in[6];     // (128,)

  float* out       = (float*)d_out;
  float* out_xyz   = out;                                        // (4,2048,3)
  float* out_feats = out + (size_t)B_SZ * M_CENT * 3;            // (4,2048,128)
  float* out_bid   = out_feats + (size_t)B_SZ * M_CENT * H2_DIM; // (4,2048,1) int32 zeros
  int*   idx_ws    = (int*)d_ws;                                 // (4,2048,32) int32, 1 MiB

  hipLaunchKernelGGL(fps_kernel, dim3(B_SZ), dim3(FPS_T), 0, stream, xyz, out_xyz);
  hipLaunchKernelGGL(ballq_kernel, dim3((B_SZ * M_CENT + 3) / 4), dim3(256), 0, stream,
                     xyz, out_xyz, idx_ws);
  hipLaunchKernelGGL(mlp_kernel, dim3(B_SZ * M_CENT), dim3(128), 0, stream,
                     xyz, feats, out_xyz, idx_ws, w1, b1, w2, b2, out_feats);
  hipMemsetAsync(out_bid, 0, (size_t)B_SZ * M_CENT * sizeof(int), stream);
}

// Round 3
// 4067.232 us; speedup vs baseline: 1.4854x; 1.0512x over previous
//
#include <hip/hip_runtime.h>
#include <cstdint>
#include <cstddef>

#define B_SZ   4
#define N_PTS  16384
#define M_CENT 2048
#define NSAMP  32
#define C_IN   64
#define H1_DIM 64
#define H2_DIM 128
#define FPS_T  512
#define PPT    (N_PTS / FPS_T)   // 32 points per thread
#define H0_STR 68                // 67 channels padded to 68 for 16B-aligned float4

typedef float v2f __attribute__((ext_vector_type(2)));

// ---------------------------------------------------------------------------
// K1: Farthest-point sampling. One block per batch. All point coords + running
// dists in registers: 512 thr x 32 pts = {xy:64, z:32, d:32} = 128 VGPRs,
// launch_bounds(512,2) -> 256 VGPR cap. Inline-asm pins make the loaded
// coords opaque so the backend cannot sink the loads back into the loop
// (round-2 pathology: VGPR=48, 398 MB/dispatch re-read, L2-BW-bound).
// (x,y) packed as float2 -> v_pk_sub/v_pk_mul (bit-identical to scalar).
// u64 (dist, N-idx) max-reduction == numpy argmax (max dist, min idx on tie).
// contract(off) + ((dx*dx+dy*dy)+dz*dz) keeps distances bit-exact vs numpy.
// ---------------------------------------------------------------------------
__global__ __launch_bounds__(FPS_T, 2) void fps_kernel(const float* __restrict__ xyz,
                                                       float* __restrict__ out_xyz) {
#pragma clang fp contract(off)
  const int b    = blockIdx.x;
  const int t    = threadIdx.x;
  const int lane = t & 63;
  const int wave = t >> 6;           // 8 waves
  const float* bx = xyz + (size_t)b * N_PTS * 3;
  float* ox = out_xyz + (size_t)b * M_CENT * 3;

  v2f   pxy[PPT];
  float pz[PPT], pd[PPT];
#pragma unroll
  for (int j = 0; j < PPT; ++j) {
    const int i = j * FPS_T + t;
    v2f v; v.x = bx[i * 3 + 0]; v.y = bx[i * 3 + 1];
    pxy[j] = v;
    pz[j]  = bx[i * 3 + 2];
    pd[j]  = 1e10f;  // BIG
  }
  // Pin: values now opaque-defined -> loads cannot be re-materialized in-loop.
#pragma unroll
  for (int j = 0; j < PPT; ++j) {
    asm volatile("" : "+v"(pxy[j]), "+v"(pz[j]));
  }

  __shared__ unsigned long long s_key[2][8];

  int cur = 0;  // reference idx0 = 0
  for (int m = 0; m < M_CENT; ++m) {
    const float cx = bx[cur * 3 + 0];   // wave-uniform broadcast (L2-hot)
    const float cy = bx[cur * 3 + 1];
    const float cz = bx[cur * 3 + 2];
    if (t == 0) { ox[m * 3 + 0] = cx; ox[m * 3 + 1] = cy; ox[m * 3 + 2] = cz; }
    if (m == M_CENT - 1) break;

    v2f cxy; cxy.x = cx; cxy.y = cy;
    float bv = -1.0f;  // dists >= 0, so first point always taken
    int   bi = 0;
#pragma unroll
    for (int j = 0; j < PPT; ++j) {
      const v2f dxy = pxy[j] - cxy;       // v_pk_sub_f32
      const v2f sq  = dxy * dxy;          // v_pk_mul_f32 (exact per-element)
      const float dz = pz[j] - cz;
      const float d  = (sq.x + sq.y) + dz * dz;   // numpy op order, no FMA
      const float nd = fminf(pd[j], d);
      pd[j] = nd;
      const bool better = nd > bv;   // strict: keeps smaller j (= smaller global idx)
      bv = better ? nd : bv;
      bi = better ? (j * FPS_T + t) : bi;
    }
    // pack: high = float bits (>=0, monotone), low = N-idx so ties -> min idx
    unsigned long long key = ((unsigned long long)__float_as_uint(bv) << 32)
                           | (unsigned int)(N_PTS - bi);
#pragma unroll
    for (int off = 32; off >= 1; off >>= 1) {
      const unsigned long long o = __shfl_xor(key, off);
      key = (key > o) ? key : o;
    }
    const int p = m & 1;
    if (lane == 0) s_key[p][wave] = key;
    __syncthreads();
    // all waves redundantly reduce the 8 per-wave keys (no 2nd barrier)
    key = s_key[p][lane & 7];
#pragma unroll
    for (int off = 4; off >= 1; off >>= 1) {
      const unsigned long long o = __shfl_xor(key, off);
      key = (key > o) ? key : o;
    }
    cur = N_PTS - (int)(key & 0xFFFFFFFFULL);
  }
}

// ---------------------------------------------------------------------------
// K2: Ball query. One wave per centroid: ballot + prefix popcount appends the
// first 32 in-radius indices in index order (== top_k(-order) semantics),
// pads with the first hit. Early exit once 32 found.
// ---------------------------------------------------------------------------
__global__ __launch_bounds__(256) void ballq_kernel(const float* __restrict__ xyz,
                                                    const float* __restrict__ new_xyz,
                                                    int* __restrict__ idx_out) {
#pragma clang fp contract(off)
  const int lane = threadIdx.x & 63;
  const int gid  = blockIdx.x * 4 + (threadIdx.x >> 6);
  if (gid >= B_SZ * M_CENT) return;
  const int b = gid >> 11;  // / M_CENT
  const float* bx = xyz + (size_t)b * N_PTS * 3;
  const float cx = new_xyz[gid * 3 + 0];
  const float cy = new_xyz[gid * 3 + 1];
  const float cz = new_xyz[gid * 3 + 2];
  const float rr = (float)(0.8 * 0.8);  // double 0.64 -> f32 (JAX weak-scalar cast)
  int* out = idx_out + (size_t)gid * NSAMP;

  int count = 0;
  int first = -1;
  for (int base = 0; base < N_PTS; base += 64) {
    const int i = base + lane;
    const float dx = bx[i * 3 + 0] - cx;
    const float dy = bx[i * 3 + 1] - cy;
    const float dz = bx[i * 3 + 2] - cz;
    const float d = (dx * dx + dy * dy) + dz * dz;
    const bool pred = d < rr;
    const unsigned long long mk = __ballot(pred);
    if (pred) {
      const int slot = count + __popcll(mk & ((1ULL << lane) - 1ULL));
      if (slot < NSAMP) out[slot] = i;
    }
    if (first < 0 && mk != 0ULL) first = base + (__ffsll((long long)mk) - 1);
    count += __popcll(mk);
    if (count >= NSAMP) break;
  }
  if (count < NSAMP) {
    for (int k = count + lane; k < NSAMP; k += 64) out[k] = first;  // centroid itself is a hit
  }
}

// ---------------------------------------------------------------------------
// K3: gather + MLP(67->64 relu, 64->128 relu) + max over 32 samples.
// One 128-thread block per centroid. h0/h1 staged in LDS; reads are
// wave-uniform float4 broadcasts; weights coalesced from L1/L2.
// ---------------------------------------------------------------------------
__global__ __launch_bounds__(128) void mlp_kernel(const float* __restrict__ xyz,
                                                  const float* __restrict__ feats,
                                                  const float* __restrict__ new_xyz,
                                                  const int* __restrict__ idx,
                                                  const float* __restrict__ w1,
                                                  const float* __restrict__ b1,
                                                  const float* __restrict__ w2,
                                                  const float* __restrict__ b2,
                                                  float* __restrict__ out_feats) {
  const int gid = blockIdx.x;
  const int t   = threadIdx.x;
  const int b   = gid >> 11;  // / M_CENT

  __shared__ float h0[NSAMP * H0_STR];
  __shared__ float h1[NSAMP * H1_DIM];
  __shared__ int   sidx[NSAMP];

  if (t < NSAMP) sidx[t] = idx[(size_t)gid * NSAMP + t];
  const float cx = new_xyz[gid * 3 + 0];
  const float cy = new_xyz[gid * 3 + 1];
  const float cz = new_xyz[gid * 3 + 2];
  __syncthreads();

  const float* bxyz = xyz + (size_t)b * N_PTS * 3;
  const float* bft  = feats + (size_t)b * N_PTS * C_IN;
  for (int e = t; e < NSAMP * 67; e += 128) {
    const int s = e / 67;
    const int c = e - s * 67;
    const int p = sidx[s];
    float v;
    if (c < 3) {
      const float pc = bxyz[p * 3 + c];
      v = pc - (c == 0 ? cx : (c == 1 ? cy : cz));
    } else {
      v = bft[(size_t)p * C_IN + (c - 3)];
    }
    h0[s * H0_STR + c] = v;
  }
  __syncthreads();

  // layer 1: col = t&63 over H1_DIM, half = t>>6 picks 16 of 32 samples
  {
    const int col  = t & 63;
    const int half = t >> 6;
    float acc[16];
    const float bb = b1[col];
#pragma unroll
    for (int s = 0; s < 16; ++s) acc[s] = bb;
    const float* h0base = h0 + (half * 16) * H0_STR;
    for (int k = 0; k < 64; k += 4) {
      const float w0v = w1[(k + 0) * H1_DIM + col];
      const float w1v = w1[(k + 1) * H1_DIM + col];
      const float w2v = w1[(k + 2) * H1_DIM + col];
      const float w3v = w1[(k + 3) * H1_DIM + col];
#pragma unroll
      for (int s = 0; s < 16; ++s) {
        const float4 h4 = *reinterpret_cast<const float4*>(h0base + s * H0_STR + k);
        acc[s] += h4.x * w0v + h4.y * w1v + h4.z * w2v + h4.w * w3v;
      }
    }
    for (int k = 64; k < 67; ++k) {
      const float wv = w1[k * H1_DIM + col];
#pragma unroll
      for (int s = 0; s < 16; ++s) acc[s] += h0base[s * H0_STR + k] * wv;
    }
#pragma unroll
    for (int s = 0; s < 16; ++s) h1[(half * 16 + s) * H1_DIM + col] = fmaxf(acc[s], 0.0f);
  }
  __syncthreads();

  // layer 2 + max-pool: col = t over H2_DIM
  {
    float acc[32];
    const float bb = b2[t];
#pragma unroll
    for (int s = 0; s < 32; ++s) acc[s] = bb;
    for (int k = 0; k < 64; k += 4) {
      const float w0v = w2[(k + 0) * H2_DIM + t];
      const float w1v = w2[(k + 1) * H2_DIM + t];
      const float w2v = w2[(k + 2) * H2_DIM + t];
      const float w3v = w2[(k + 3) * H2_DIM + t];
#pragma unroll
      for (int s = 0; s < 32; ++s) {
        const float4 h4 = *reinterpret_cast<const float4*>(&h1[s * H1_DIM + k]);
        acc[s] += h4.x * w0v + h4.y * w1v + h4.z * w2v + h4.w * w3v;
      }
    }
    float mx = 0.0f;  // max(relu(v)) == max(0, max(v))
#pragma unroll
    for (int s = 0; s < 32; ++s) mx = fmaxf(mx, acc[s]);
    out_feats[(size_t)gid * H2_DIM + t] = mx;
  }
}

// ---------------------------------------------------------------------------
extern "C" void kernel_launch(void* const* d_in, const int* in_sizes, int n_in,
                              void* d_out, int out_size, void* d_ws, size_t ws_size,
                              hipStream_t stream) {
  const float* xyz   = (const float*)d_in[0];  // (4,16384,3) f32
  const float* feats = (const float*)d_in[1];  // (4,16384,64) f32
  // d_in[2] = bid (unused; output bid is all zeros)
  const float* w1 = (const float*)d_in[3];     // (67,64)
  const float* b1 = (const float*)d_in[4];     // (64,)
  const float* w2 = (const float*)d_in[5];     // (64,128)
  const float* b2 = (const float*)d_in[6];     // (128,)

  float* out       = (float*)d_out;
  float* out_xyz   = out;                                        // (4,2048,3)
  float* out_feats = out + (size_t)B_SZ * M_CENT * 3;            // (4,2048,128)
  float* out_bid   = out_feats + (size_t)B_SZ * M_CENT * H2_DIM; // (4,2048,1) int32 zeros
  int*   idx_ws    = (int*)d_ws;                                 // (4,2048,32) int32, 1 MiB

  hipLaunchKernelGGL(fps_kernel, dim3(B_SZ), dim3(FPS_T), 0, stream, xyz, out_xyz);
  hipLaunchKernelGGL(ballq_kernel, dim3((B_SZ * M_CENT + 3) / 4), dim3(256), 0, stream,
                     xyz, out_xyz, idx_ws);
  hipLaunchKernelGGL(mlp_kernel, dim3(B_SZ * M_CENT), dim3(128), 0, stream,
                     xyz, feats, out_xyz, idx_ws, w1, b1, w2, b2, out_feats);
  hipMemsetAsync(out_bid, 0, (size_t)B_SZ * M_CENT * sizeof(int), stream);
}